// Round 1
// baseline (270.347 us; speedup 1.0000x reference)
//
#include <hip/hip_runtime.h>

using u16 = unsigned short;
typedef __attribute__((ext_vector_type(8))) __bf16 bf16x8;
typedef __attribute__((ext_vector_type(4))) float f32x4;
typedef __attribute__((ext_vector_type(4))) float f4v;
typedef __attribute__((ext_vector_type(8))) u16 u16x8;

__device__ __forceinline__ u16 f2bf(float f) {
  unsigned u = __float_as_uint(f);
  u += 0x7fffu + ((u >> 16) & 1u);   // round-to-nearest-even
  return (u16)(u >> 16);
}

__device__ __forceinline__ void gload16(const void* g, void* l) {
  __builtin_amdgcn_global_load_lds(
      (const __attribute__((address_space(1))) unsigned int*)g,
      (__attribute__((address_space(3))) unsigned int*)l, 16, 0, 0);
}

// ---------------------------------------------------------------- cast f32->bf16
__global__ __launch_bounds__(256) void cast_f32_bf16(const float* __restrict__ in,
                                                     u16* __restrict__ out) {
  size_t i = ((size_t)blockIdx.x * 256 + threadIdx.x) * 8;
  f4v a = *reinterpret_cast<const f4v*>(in + i);
  f4v b = *reinterpret_cast<const f4v*>(in + i + 4);
  u16x8 r;
  r[0] = f2bf(a[0]); r[1] = f2bf(a[1]); r[2] = f2bf(a[2]); r[3] = f2bf(a[3]);
  r[4] = f2bf(b[0]); r[5] = f2bf(b[1]); r[6] = f2bf(b[2]); r[7] = f2bf(b[3]);
  *reinterpret_cast<u16x8*>(out + i) = r;
}

// ---------------------------------------------------------------- bf16 transpose
// in: [4][2048][1024]  -> out: [4][1024][2048]
__global__ __launch_bounds__(256) void transpose_bf16k(const u16* __restrict__ in,
                                                       u16* __restrict__ out) {
  __shared__ u16 t[64][65];
  int c0 = blockIdx.x * 64, r0 = blockIdx.y * 64;
  size_t zb = (size_t)blockIdx.z * 2048 * 1024;
  const u16* I = in + zb;
  u16* O = out + zb;
  int tx = threadIdx.x & 63, ty = threadIdx.x >> 6;
  #pragma unroll
  for (int i = 0; i < 64; i += 4)
    t[ty + i][tx] = I[(size_t)(r0 + ty + i) * 1024 + c0 + tx];
  __syncthreads();
  #pragma unroll
  for (int i = 0; i < 64; i += 4)
    O[(size_t)(c0 + ty + i) * 2048 + r0 + tx] = t[tx][ty + i];
}

// ---------------------------------------------------------------- GEMM  C = alpha * A . B^T
// A: [M][K] bf16 (lda), B: [N][K] bf16 (ldb), C: [M][N] (ldc), batched via blockIdx.z.
// MODE 0: plain.  MODE 1: causal QK^T — skip tiles with bn>bm.  MODE 2: causal PV — K clipped.
#define BM 128
#define BN 128
#define BK 32

template<typename OutT, int MODE>
__global__ __launch_bounds__(256) void gemm_bt(
    const u16* __restrict__ A, const u16* __restrict__ B, OutT* __restrict__ C,
    int M, int N, int K, int lda, int ldb, int ldc,
    size_t sA, size_t sB, size_t sC, float alpha) {
  int bn = blockIdx.x, bm = blockIdx.y, bz = blockIdx.z;
  if (MODE == 1 && bn > bm) return;
  int kEnd = (MODE == 2) ? ((K < (bm + 1) * BM) ? K : (bm + 1) * BM) : K;

  __shared__ __align__(16) u16 As[BM * BK];
  __shared__ __align__(16) u16 Bs[BN * BK];

  const int tid = threadIdx.x;
  const int lane = tid & 63, wave = tid >> 6;
  const int wr = wave >> 1, wc = wave & 1;

  const u16* Ag = A + sA * bz + (size_t)bm * BM * lda;
  const u16* Bg = B + sB * bz + (size_t)bn * BN * ldb;

  // staging: 8 chunks of 1024B per tile; wave w owns chunks {w, w+4}
  const int ch0 = wave, ch1 = wave + 4;
  const int e0 = ch0 * 512 + lane * 8, e1 = ch1 * 512 + lane * 8;
  const int r0 = e0 >> 5, c0 = e0 & 31, r1 = e1 >> 5, c1 = e1 & 31;
  const u16* a0 = Ag + (size_t)r0 * lda + c0;
  const u16* a1 = Ag + (size_t)r1 * lda + c1;
  const u16* b0 = Bg + (size_t)r0 * ldb + c0;
  const u16* b1 = Bg + (size_t)r1 * ldb + c1;
  u16* la0 = &As[ch0 * 512];
  u16* la1 = &As[ch1 * 512];
  u16* lb0 = &Bs[ch0 * 512];
  u16* lb1 = &Bs[ch1 * 512];

  f32x4 acc[4][4] = {};

  const int fr = lane & 15, kq = (lane >> 4) * 8;

  for (int k0 = 0; k0 < kEnd; k0 += BK) {
    gload16(a0 + k0, la0);
    gload16(a1 + k0, la1);
    gload16(b0 + k0, lb0);
    gload16(b1 + k0, lb1);
    __syncthreads();
    bf16x8 af[4], bfv[4];
    #pragma unroll
    for (int m = 0; m < 4; ++m)
      af[m] = *reinterpret_cast<const bf16x8*>(&As[(wr * 64 + m * 16 + fr) * BK + kq]);
    #pragma unroll
    for (int n = 0; n < 4; ++n)
      bfv[n] = *reinterpret_cast<const bf16x8*>(&Bs[(wc * 64 + n * 16 + fr) * BK + kq]);
    #pragma unroll
    for (int m = 0; m < 4; ++m)
      #pragma unroll
      for (int n = 0; n < 4; ++n)
        acc[m][n] = __builtin_amdgcn_mfma_f32_16x16x32_bf16(af[m], bfv[n], acc[m][n], 0, 0, 0);
    __syncthreads();
  }

  OutT* Cg = C + sC * bz;
  const int row0 = bm * BM + wr * 64 + (lane >> 4) * 4;
  const int col0 = bn * BN + wc * 64 + fr;
  #pragma unroll
  for (int m = 0; m < 4; ++m)
    #pragma unroll
    for (int n = 0; n < 4; ++n) {
      #pragma unroll
      for (int j = 0; j < 4; ++j) {
        float val = acc[m][n][j] * alpha;
        size_t idx = (size_t)(row0 + m * 16 + j) * ldc + (col0 + n * 16);
        if constexpr (sizeof(OutT) == 2) Cg[idx] = f2bf(val);
        else Cg[idx] = val;
      }
    }
}

// ---------------------------------------------------------------- causal softmax (in-place)
// scores: [4][2048][2048] f32. Row r: softmax over t<=s, write bf16 P into the
// same row slot (first 4KB of the 8KB row => ldp = 4096 u16 elements).
__global__ __launch_bounds__(256) void softmax_causal(float* __restrict__ sc) {
  int r = blockIdx.x;          // 0..8191
  int s = r & 2047;
  float* row = sc + (size_t)r * 2048;
  int tid = threadIdx.x;
  f4v x0 = reinterpret_cast<const f4v*>(row)[tid * 2];
  f4v x1 = reinterpret_cast<const f4v*>(row)[tid * 2 + 1];
  float v[8] = {x0[0], x0[1], x0[2], x0[3], x1[0], x1[1], x1[2], x1[3]};
  int t0 = tid * 8;
  float mx = -1e30f;
  #pragma unroll
  for (int j = 0; j < 8; ++j) {
    v[j] = ((t0 + j) <= s) ? v[j] : -1e30f;
    mx = fmaxf(mx, v[j]);
  }
  #pragma unroll
  for (int o = 32; o; o >>= 1) mx = fmaxf(mx, __shfl_xor(mx, o, 64));
  __shared__ float red[8];
  if ((tid & 63) == 0) red[tid >> 6] = mx;
  __syncthreads();
  mx = fmaxf(fmaxf(red[0], red[1]), fmaxf(red[2], red[3]));
  float p[8];
  float sum = 0.f;
  #pragma unroll
  for (int j = 0; j < 8; ++j) {
    p[j] = ((t0 + j) <= s) ? __expf(v[j] - mx) : 0.f;
    sum += p[j];
  }
  #pragma unroll
  for (int o = 32; o; o >>= 1) sum += __shfl_xor(sum, o, 64);
  if ((tid & 63) == 0) red[4 + (tid >> 6)] = sum;
  __syncthreads();
  sum = red[4] + red[5] + red[6] + red[7];
  float inv = 1.0f / sum;
  u16x8 o8;
  #pragma unroll
  for (int j = 0; j < 8; ++j) o8[j] = f2bf(p[j] * inv);
  reinterpret_cast<u16x8*>(row)[tid] = o8;
}

// ---------------------------------------------------------------- launcher
extern "C" void kernel_launch(void* const* d_in, const int* in_sizes, int n_in,
                              void* d_out, int out_size, void* d_ws, size_t ws_size,
                              hipStream_t stream) {
  const float* q  = (const float*)d_in[0];
  const float* k  = (const float*)d_in[1];
  const float* v  = (const float*)d_in[2];
  // d_in[3] = attn_mask (causal tril) — handled analytically
  const float* Wq = (const float*)d_in[4];
  const float* Wk = (const float*)d_in[5];
  const float* Wv = (const float*)d_in[6];
  float* out = (float*)d_out;
  char* ws = (char*)d_ws;

  const size_t MB = 1024ull * 1024ull;
  u16* qb  = (u16*)(ws + 0 * MB);    // 16MB  (dead after Q proj)
  u16* kb  = (u16*)(ws + 16 * MB);   // 16MB  (dead after K proj)
  u16* vb  = (u16*)(ws + 32 * MB);   // 16MB  (dead after V proj)
  u16* wqb = (u16*)(ws + 48 * MB);   // 2MB
  u16* wkb = (u16*)(ws + 50 * MB);   // 2MB
  u16* wvb = (u16*)(ws + 52 * MB);   // 2MB
  u16* Vp  = (u16*)(ws + 54 * MB);   // 16MB  (dead after transpose)
  u16* Vt  = (u16*)(ws + 70 * MB);   // 16MB
  u16* Kp  = (u16*)(ws + 86 * MB);   // 16MB
  u16* Qp  = (u16*)(ws + 102 * MB);  // 16MB  -> peak 118MB
  float* sc = (float*)ws;            // 64MB, overlays dead casts+Vp

  // 1. casts
  cast_f32_bf16<<<4096, 256, 0, stream>>>(q, qb);
  cast_f32_bf16<<<4096, 256, 0, stream>>>(k, kb);
  cast_f32_bf16<<<4096, 256, 0, stream>>>(v, vb);
  cast_f32_bf16<<<512, 256, 0, stream>>>(Wq, wqb);
  cast_f32_bf16<<<512, 256, 0, stream>>>(Wk, wkb);
  cast_f32_bf16<<<512, 256, 0, stream>>>(Wv, wvb);

  // 2. projections: X[8192][1024] . W[1024][1024]^T -> bf16
  dim3 gProj(8, 64, 1);
  gemm_bt<u16, 0><<<gProj, 256, 0, stream>>>(qb, wqb, Qp, 8192, 1024, 1024,
                                             1024, 1024, 1024, 0, 0, 0, 1.0f);
  gemm_bt<u16, 0><<<gProj, 256, 0, stream>>>(kb, wkb, Kp, 8192, 1024, 1024,
                                             1024, 1024, 1024, 0, 0, 0, 1.0f);
  gemm_bt<u16, 0><<<gProj, 256, 0, stream>>>(vb, wvb, Vp, 8192, 1024, 1024,
                                             1024, 1024, 1024, 0, 0, 0, 1.0f);

  // 3. V transpose -> Vt[4][1024][2048]
  transpose_bf16k<<<dim3(16, 32, 4), 256, 0, stream>>>(Vp, Vt);

  // 4. QK^T (scaled, causal block-skip) -> scores f32 [4][2048][2048]
  dim3 gQK(16, 16, 4);
  gemm_bt<float, 1><<<gQK, 256, 0, stream>>>(Qp, Kp, sc, 2048, 2048, 1024,
                                             1024, 1024, 2048,
                                             (size_t)2048 * 1024, (size_t)2048 * 1024,
                                             (size_t)2048 * 2048, 0.03125f);

  // 5. causal softmax, bf16 P written in place (ldp = 4096 u16)
  softmax_causal<<<8192, 256, 0, stream>>>(sc);

  // 6. PV: P[2048][2048](lda 4096) . Vt[1024][2048]^T -> out f32, K clipped causally
  dim3 gPV(8, 16, 4);
  gemm_bt<float, 2><<<gPV, 256, 0, stream>>>((u16*)ws, Vt, out, 2048, 1024, 2048,
                                             4096, 2048, 1024,
                                             (size_t)2048 * 4096, (size_t)1024 * 2048,
                                             (size_t)2048 * 1024, 1.0f);
}

// Round 2
// 224.982 us; speedup vs baseline: 1.2016x; 1.2016x over previous
//
#include <hip/hip_runtime.h>

using u16 = unsigned short;
typedef __attribute__((ext_vector_type(8))) __bf16 bf16x8;
typedef __attribute__((ext_vector_type(4))) float f32x4;
typedef __attribute__((ext_vector_type(4))) float f4v;
typedef __attribute__((ext_vector_type(8))) u16 u16x8;

__device__ __forceinline__ u16 f2bf(float f) {
  unsigned u = __float_as_uint(f);
  u += 0x7fffu + ((u >> 16) & 1u);   // round-to-nearest-even
  return (u16)(u >> 16);
}

__device__ __forceinline__ void gload16(const void* g, void* l) {
  __builtin_amdgcn_global_load_lds(
      (const __attribute__((address_space(1))) unsigned int*)g,
      (__attribute__((address_space(3))) unsigned int*)l, 16, 0, 0);
}

// ---------------------------------------------------------------- cast f32->bf16 (3 tensors)
// outputs are contiguous: out + z*stride
__global__ __launch_bounds__(256) void cast3_f32_bf16(
    const float* __restrict__ p0, const float* __restrict__ p1,
    const float* __restrict__ p2, u16* __restrict__ out, size_t ostride) {
  int z = blockIdx.z;
  const float* in = (z == 0) ? p0 : (z == 1) ? p1 : p2;
  size_t i = ((size_t)blockIdx.x * 256 + threadIdx.x) * 8;
  f4v a = *reinterpret_cast<const f4v*>(in + i);
  f4v b = *reinterpret_cast<const f4v*>(in + i + 4);
  u16x8 r;
  r[0] = f2bf(a[0]); r[1] = f2bf(a[1]); r[2] = f2bf(a[2]); r[3] = f2bf(a[3]);
  r[4] = f2bf(b[0]); r[5] = f2bf(b[1]); r[6] = f2bf(b[2]); r[7] = f2bf(b[3]);
  *reinterpret_cast<u16x8*>(out + z * ostride + i) = r;
}

// ---------------------------------------------------------------- bf16 transpose
// in: [4][2048][1024]  -> out: [4][1024][2048]
__global__ __launch_bounds__(256) void transpose_bf16k(const u16* __restrict__ in,
                                                       u16* __restrict__ out) {
  __shared__ u16 t[64][65];
  int c0 = blockIdx.x * 64, r0 = blockIdx.y * 64;
  size_t zb = (size_t)blockIdx.z * 2048 * 1024;
  const u16* I = in + zb;
  u16* O = out + zb;
  int tx = threadIdx.x & 63, ty = threadIdx.x >> 6;
  #pragma unroll
  for (int i = 0; i < 64; i += 4)
    t[ty + i][tx] = I[(size_t)(r0 + ty + i) * 1024 + c0 + tx];
  __syncthreads();
  #pragma unroll
  for (int i = 0; i < 64; i += 4)
    O[(size_t)(c0 + ty + i) * 2048 + r0 + tx] = t[tx][ty + i];
}

// ---------------------------------------------------------------- GEMM  C = alpha * A . B^T
// A: [M][K] bf16 (lda), B: [N][K] bf16 (ldb), C: [M][N] (ldc), batched via blockIdx.z.
// MODE 1: causal QK^T — skip tiles with bn>bm.
// MODE 2: causal PV  — K clipped to (bm+1)*BM.
// MODE 3: stacked 3-way projection — bm>>6 selects weight slab (B + which*sB) and
//         output pointer {C, C1, C2}; A rows are globally stacked (sA = per-slab stride).
#define BM 128
#define BN 128
#define BK 32

template<typename OutT, int MODE>
__global__ __launch_bounds__(256) void gemm_bt(
    const u16* __restrict__ A, const u16* __restrict__ B, OutT* __restrict__ C,
    int K, int lda, int ldb, int ldc,
    size_t sA, size_t sB, size_t sC, float alpha,
    OutT* __restrict__ C1, OutT* __restrict__ C2) {
  int bn = blockIdx.x, bm = blockIdx.y, bz = blockIdx.z;
  if (MODE == 1 && bn > bm) return;
  int kEnd = K;
  if (MODE == 2) kEnd = (K < (bm + 1) * BM) ? K : (bm + 1) * BM;

  const u16* Ag;
  const u16* Bg;
  OutT* Cg;
  int bmL = bm;
  if (MODE == 3) {
    int which = bm >> 6;
    bmL = bm & 63;
    Ag = A + (size_t)which * sA + (size_t)bmL * BM * lda;
    Bg = B + (size_t)which * sB + (size_t)bn * BN * ldb;
    Cg = (which == 0) ? C : (which == 1) ? C1 : C2;
  } else {
    Ag = A + sA * bz + (size_t)bm * BM * lda;
    Bg = B + sB * bz + (size_t)bn * BN * ldb;
    Cg = C + sC * bz;
  }

  __shared__ __align__(16) u16 As[2][BM * BK];
  __shared__ __align__(16) u16 Bs[2][BN * BK];

  const int tid = threadIdx.x;
  const int lane = tid & 63, wave = tid >> 6;
  const int wr = wave >> 1, wc = wave & 1;

  // staging: 8 chunks of 1024B per tile; wave w owns chunks {w, w+4}
  const int ch0 = wave, ch1 = wave + 4;
  const int e0 = ch0 * 512 + lane * 8, e1 = ch1 * 512 + lane * 8;
  const int r0 = e0 >> 5, c0 = e0 & 31, r1 = e1 >> 5, c1 = e1 & 31;
  const u16* a0 = Ag + (size_t)r0 * lda + c0;
  const u16* a1 = Ag + (size_t)r1 * lda + c1;
  const u16* b0 = Bg + (size_t)r0 * ldb + c0;
  const u16* b1 = Bg + (size_t)r1 * ldb + c1;

  f32x4 acc[4][4] = {};

  const int fr = lane & 15, kq = (lane >> 4) * 8;
  const int nt = kEnd / BK;

  // prologue: stage tile 0 into buffer 0
  gload16(a0, &As[0][ch0 * 512]);
  gload16(a1, &As[0][ch1 * 512]);
  gload16(b0, &Bs[0][ch0 * 512]);
  gload16(b1, &Bs[0][ch1 * 512]);
  __syncthreads();

  for (int t = 0; t < nt; ++t) {
    const int cur = t & 1;
    if (t + 1 < nt) {       // prefetch next tile into the other buffer
      const int k0 = (t + 1) * BK;
      gload16(a0 + k0, &As[cur ^ 1][ch0 * 512]);
      gload16(a1 + k0, &As[cur ^ 1][ch1 * 512]);
      gload16(b0 + k0, &Bs[cur ^ 1][ch0 * 512]);
      gload16(b1 + k0, &Bs[cur ^ 1][ch1 * 512]);
    }
    bf16x8 af[4], bfv[4];
    #pragma unroll
    for (int m = 0; m < 4; ++m)
      af[m] = *reinterpret_cast<const bf16x8*>(&As[cur][(wr * 64 + m * 16 + fr) * BK + kq]);
    #pragma unroll
    for (int n = 0; n < 4; ++n)
      bfv[n] = *reinterpret_cast<const bf16x8*>(&Bs[cur][(wc * 64 + n * 16 + fr) * BK + kq]);
    #pragma unroll
    for (int m = 0; m < 4; ++m)
      #pragma unroll
      for (int n = 0; n < 4; ++n)
        acc[m][n] = __builtin_amdgcn_mfma_f32_16x16x32_bf16(af[m], bfv[n], acc[m][n], 0, 0, 0);
    __syncthreads();  // implicit vmcnt(0): waits the prefetch issued ~300 cyc ago
  }

  const int row0 = bmL * BM + wr * 64 + (lane >> 4) * 4;
  const int col0 = bn * BN + wc * 64 + fr;
  #pragma unroll
  for (int m = 0; m < 4; ++m)
    #pragma unroll
    for (int n = 0; n < 4; ++n) {
      #pragma unroll
      for (int j = 0; j < 4; ++j) {
        float val = acc[m][n][j] * alpha;
        size_t idx = (size_t)(row0 + m * 16 + j) * ldc + (col0 + n * 16);
        if constexpr (sizeof(OutT) == 2) Cg[idx] = f2bf(val);
        else Cg[idx] = val;
      }
    }
}

// ---------------------------------------------------------------- causal softmax (in-place)
// scores: [4][2048][2048] f32. Row r: softmax over t<=s, write bf16 P into the
// same row slot (first 4KB of the 8KB row => ldp = 4096 u16 elements).
__global__ __launch_bounds__(256) void softmax_causal(float* __restrict__ sc) {
  int r = blockIdx.x;          // 0..8191
  int s = r & 2047;
  float* row = sc + (size_t)r * 2048;
  int tid = threadIdx.x;
  f4v x0 = reinterpret_cast<const f4v*>(row)[tid * 2];
  f4v x1 = reinterpret_cast<const f4v*>(row)[tid * 2 + 1];
  float v[8] = {x0[0], x0[1], x0[2], x0[3], x1[0], x1[1], x1[2], x1[3]};
  int t0 = tid * 8;
  float mx = -1e30f;
  #pragma unroll
  for (int j = 0; j < 8; ++j) {
    v[j] = ((t0 + j) <= s) ? v[j] : -1e30f;
    mx = fmaxf(mx, v[j]);
  }
  #pragma unroll
  for (int o = 32; o; o >>= 1) mx = fmaxf(mx, __shfl_xor(mx, o, 64));
  __shared__ float red[8];
  if ((tid & 63) == 0) red[tid >> 6] = mx;
  __syncthreads();
  mx = fmaxf(fmaxf(red[0], red[1]), fmaxf(red[2], red[3]));
  float p[8];
  float sum = 0.f;
  #pragma unroll
  for (int j = 0; j < 8; ++j) {
    p[j] = ((t0 + j) <= s) ? __expf(v[j] - mx) : 0.f;
    sum += p[j];
  }
  #pragma unroll
  for (int o = 32; o; o >>= 1) sum += __shfl_xor(sum, o, 64);
  if ((tid & 63) == 0) red[4 + (tid >> 6)] = sum;
  __syncthreads();
  sum = red[4] + red[5] + red[6] + red[7];
  float inv = 1.0f / sum;
  u16x8 o8;
  #pragma unroll
  for (int j = 0; j < 8; ++j) o8[j] = f2bf(p[j] * inv);
  reinterpret_cast<u16x8*>(row)[tid] = o8;
}

// ---------------------------------------------------------------- launcher
extern "C" void kernel_launch(void* const* d_in, const int* in_sizes, int n_in,
                              void* d_out, int out_size, void* d_ws, size_t ws_size,
                              hipStream_t stream) {
  const float* q  = (const float*)d_in[0];
  const float* k  = (const float*)d_in[1];
  const float* v  = (const float*)d_in[2];
  // d_in[3] = attn_mask (causal tril) — handled analytically
  const float* Wq = (const float*)d_in[4];
  const float* Wk = (const float*)d_in[5];
  const float* Wv = (const float*)d_in[6];
  float* out = (float*)d_out;
  char* ws = (char*)d_ws;

  const size_t MB = 1024ull * 1024ull;
  u16* qb  = (u16*)(ws + 0 * MB);    // 48MB x/k/v bf16 (dead after proj)
  u16* wqb = (u16*)(ws + 48 * MB);   // 6MB  weights bf16 (dead after proj)
  u16* Vp  = (u16*)(ws + 54 * MB);   // 16MB (dead after transpose)
  u16* Vt  = (u16*)(ws + 70 * MB);   // 16MB
  u16* Kp  = (u16*)(ws + 86 * MB);   // 16MB
  u16* Qp  = (u16*)(ws + 102 * MB);  // 16MB  -> peak 118MB
  float* sc = (float*)ws;            // 64MB, overlays dead casts+weights+Vp

  // 1. casts (2 launches)
  cast3_f32_bf16<<<dim3(4096, 1, 3), 256, 0, stream>>>(q, k, v, qb, 8ull * MB);
  cast3_f32_bf16<<<dim3(512, 1, 3), 256, 0, stream>>>(Wq, Wk, Wv, wqb, 1ull * MB);

  // 2. all 3 projections in ONE stacked launch: 1536 blocks
  //    bm slab 0-63 -> Q, 64-127 -> K, 128-191 -> V
  gemm_bt<u16, 3><<<dim3(8, 192, 1), 256, 0, stream>>>(
      qb, wqb, Qp, 1024, 1024, 1024, 1024,
      8ull * MB, 1ull * MB, 0, 1.0f, Kp, Vp);

  // 3. V transpose -> Vt[4][1024][2048]
  transpose_bf16k<<<dim3(16, 32, 4), 256, 0, stream>>>(Vp, Vt);

  // 4. QK^T (scaled, causal block-skip) -> scores f32 [4][2048][2048]
  gemm_bt<float, 1><<<dim3(16, 16, 4), 256, 0, stream>>>(
      Qp, Kp, sc, 1024, 1024, 1024, 2048,
      (size_t)2048 * 1024, (size_t)2048 * 1024, (size_t)2048 * 2048, 0.03125f,
      nullptr, nullptr);

  // 5. causal softmax, bf16 P written in place (ldp = 4096 u16)
  softmax_causal<<<8192, 256, 0, stream>>>(sc);

  // 6. PV: P[2048][2048](lda 4096) . Vt[1024][2048]^T -> out f32, K clipped causally
  gemm_bt<float, 2><<<dim3(8, 16, 4), 256, 0, stream>>>(
      (u16*)ws, Vt, out, 2048, 4096, 2048, 1024,
      (size_t)2048 * 4096, (size_t)1024 * 2048, (size_t)2048 * 1024, 1.0f,
      nullptr, nullptr);
}

// Round 3
// 187.335 us; speedup vs baseline: 1.4431x; 1.2010x over previous
//
#include <hip/hip_runtime.h>
#include <math.h>

using u16 = unsigned short;
typedef __attribute__((ext_vector_type(8))) __bf16 bf16x8;
typedef __attribute__((ext_vector_type(4))) float f32x4;
typedef __attribute__((ext_vector_type(4))) float f4v;
typedef __attribute__((ext_vector_type(8))) u16 u16x8;

__device__ __forceinline__ u16 f2bf(float f) {
  unsigned u = __float_as_uint(f);
  u += 0x7fffu + ((u >> 16) & 1u);   // round-to-nearest-even
  return (u16)(u >> 16);
}

__device__ __forceinline__ void gload16(const void* g, void* l) {
  __builtin_amdgcn_global_load_lds(
      (const __attribute__((address_space(1))) unsigned int*)g,
      (__attribute__((address_space(3))) unsigned int*)l, 16, 0, 0);
}

// ---------------------------------------------------------------- cast f32->bf16 (3 tensors)
__global__ __launch_bounds__(256) void cast3_f32_bf16(
    const float* __restrict__ p0, const float* __restrict__ p1,
    const float* __restrict__ p2, u16* __restrict__ out, size_t ostride) {
  int z = blockIdx.z;
  const float* in = (z == 0) ? p0 : (z == 1) ? p1 : p2;
  size_t i = ((size_t)blockIdx.x * 256 + threadIdx.x) * 8;
  f4v a = *reinterpret_cast<const f4v*>(in + i);
  f4v b = *reinterpret_cast<const f4v*>(in + i + 4);
  u16x8 r;
  r[0] = f2bf(a[0]); r[1] = f2bf(a[1]); r[2] = f2bf(a[2]); r[3] = f2bf(a[3]);
  r[4] = f2bf(b[0]); r[5] = f2bf(b[1]); r[6] = f2bf(b[2]); r[7] = f2bf(b[3]);
  *reinterpret_cast<u16x8*>(out + z * ostride + i) = r;
}

// ---------------------------------------------------------------- bf16 transpose
// in: [4][2048][1024]  -> out: [4][1024][2048]
__global__ __launch_bounds__(256) void transpose_bf16k(const u16* __restrict__ in,
                                                       u16* __restrict__ out) {
  __shared__ u16 t[64][65];
  int c0 = blockIdx.x * 64, r0 = blockIdx.y * 64;
  size_t zb = (size_t)blockIdx.z * 2048 * 1024;
  const u16* I = in + zb;
  u16* O = out + zb;
  int tx = threadIdx.x & 63, ty = threadIdx.x >> 6;
  #pragma unroll
  for (int i = 0; i < 64; i += 4)
    t[ty + i][tx] = I[(size_t)(r0 + ty + i) * 1024 + c0 + tx];
  __syncthreads();
  #pragma unroll
  for (int i = 0; i < 64; i += 4)
    O[(size_t)(c0 + ty + i) * 2048 + r0 + tx] = t[tx][ty + i];
}

// ---------------------------------------------------------------- GEMM  C = alpha * A . B^T
// Flat 1-D grids with mode-specific block-index decode:
// MODE 3: stacked 3-way projection, XCD-swizzled, bn-fastest (A-panel L2 reuse).
// MODE 1: causal QK^T, triangular-packed lower-tri tiles, XCD-swizzled.
// MODE 2: causal PV, K clipped to (bm+1)*BM, longest-blocks-first, NO swizzle
//         (XCD chunking would concentrate long blocks on few XCDs).
#define BM 128
#define BN 128
#define BK 32

template<typename OutT, int MODE>
__global__ __launch_bounds__(256) void gemm_bt(
    const u16* __restrict__ A, const u16* __restrict__ B, OutT* __restrict__ C,
    int K, int lda, int ldb, int ldc,
    size_t sA, size_t sB, size_t sC, float alpha,
    OutT* __restrict__ C1, OutT* __restrict__ C2) {
  int bn, bm, bz = 0;
  int kEnd = K;
  const u16* Ag;
  const u16* Bg;
  OutT* Cg;

  if (MODE == 3) {                       // grid 1536
    int h = blockIdx.x;
    int l = (h & 7) * 192 + (h >> 3);    // bijective XCD chunking
    bn = l & 7;
    int bm192 = l >> 3;
    int which = bm192 >> 6;
    bm = bm192 & 63;
    Ag = A + (size_t)which * sA + (size_t)bm * BM * lda;
    Bg = B + (size_t)which * sB + (size_t)bn * BN * ldb;
    Cg = (which == 0) ? C : (which == 1) ? C1 : C2;
  } else if (MODE == 1) {                // grid 544 = 4 * 136 lower-tri tiles
    int h = blockIdx.x;
    int l = (h & 7) * 68 + (h >> 3);
    bz = l / 136;
    int t = l % 136;
    bm = (int)((sqrtf(8.f * (float)t + 1.f) - 1.f) * 0.5f);
    while ((bm + 1) * (bm + 2) / 2 <= t) ++bm;
    while (bm * (bm + 1) / 2 > t) --bm;
    bn = t - bm * (bm + 1) / 2;
    Ag = A + sA * bz + (size_t)bm * BM * lda;
    Bg = B + sB * bz + (size_t)bn * BN * ldb;
    Cg = C + sC * bz;
  } else {                               // MODE 2, grid 512
    int l = blockIdx.x;
    bm = 15 - (l >> 5);                  // longest kEnd first
    int rest = l & 31;
    bz = rest >> 3;
    bn = rest & 7;
    kEnd = (K < (bm + 1) * BM) ? K : (bm + 1) * BM;
    Ag = A + sA * bz + (size_t)bm * BM * lda;
    Bg = B + sB * bz + (size_t)bn * BN * ldb;
    Cg = C + sC * bz;
  }

  __shared__ __align__(16) u16 As[2][BM * BK];
  __shared__ __align__(16) u16 Bs[2][BN * BK];

  const int tid = threadIdx.x;
  const int lane = tid & 63, wave = tid >> 6;
  const int wr = wave >> 1, wc = wave & 1;

  // staging: 8 chunks of 1024B per tile; wave w owns chunks {w, w+4}
  const int ch0 = wave, ch1 = wave + 4;
  const int e0 = ch0 * 512 + lane * 8, e1 = ch1 * 512 + lane * 8;
  const int r0 = e0 >> 5, c0 = e0 & 31, r1 = e1 >> 5, c1 = e1 & 31;
  const u16* a0 = Ag + (size_t)r0 * lda + c0;
  const u16* a1 = Ag + (size_t)r1 * lda + c1;
  const u16* b0 = Bg + (size_t)r0 * ldb + c0;
  const u16* b1 = Bg + (size_t)r1 * ldb + c1;

  f32x4 acc[4][4] = {};

  const int fr = lane & 15, kq = (lane >> 4) * 8;
  const int nt = kEnd / BK;

  // prologue: stage tile 0 into buffer 0
  gload16(a0, &As[0][ch0 * 512]);
  gload16(a1, &As[0][ch1 * 512]);
  gload16(b0, &Bs[0][ch0 * 512]);
  gload16(b1, &Bs[0][ch1 * 512]);
  __syncthreads();

  for (int t = 0; t < nt; ++t) {
    const int cur = t & 1;
    if (t + 1 < nt) {       // prefetch next tile into the other buffer
      const int k0 = (t + 1) * BK;
      gload16(a0 + k0, &As[cur ^ 1][ch0 * 512]);
      gload16(a1 + k0, &As[cur ^ 1][ch1 * 512]);
      gload16(b0 + k0, &Bs[cur ^ 1][ch0 * 512]);
      gload16(b1 + k0, &Bs[cur ^ 1][ch1 * 512]);
    }
    bf16x8 af[4], bfv[4];
    #pragma unroll
    for (int m = 0; m < 4; ++m)
      af[m] = *reinterpret_cast<const bf16x8*>(&As[cur][(wr * 64 + m * 16 + fr) * BK + kq]);
    #pragma unroll
    for (int n = 0; n < 4; ++n)
      bfv[n] = *reinterpret_cast<const bf16x8*>(&Bs[cur][(wc * 64 + n * 16 + fr) * BK + kq]);
    #pragma unroll
    for (int m = 0; m < 4; ++m)
      #pragma unroll
      for (int n = 0; n < 4; ++n)
        acc[m][n] = __builtin_amdgcn_mfma_f32_16x16x32_bf16(af[m], bfv[n], acc[m][n], 0, 0, 0);
    __syncthreads();  // implicit vmcnt(0): waits the prefetch issued one phase ago
  }

  const int row0 = bm * BM + wr * 64 + (lane >> 4) * 4;
  const int col0 = bn * BN + wc * 64 + fr;
  #pragma unroll
  for (int m = 0; m < 4; ++m)
    #pragma unroll
    for (int n = 0; n < 4; ++n) {
      #pragma unroll
      for (int j = 0; j < 4; ++j) {
        float val = acc[m][n][j] * alpha;
        size_t idx = (size_t)(row0 + m * 16 + j) * ldc + (col0 + n * 16);
        if constexpr (sizeof(OutT) == 2) Cg[idx] = f2bf(val);
        else Cg[idx] = val;
      }
    }
}

// ---------------------------------------------------------------- causal softmax (in-place)
// scores: [4][2048][2048] f32. Row r: softmax over t<=s, write bf16 P into the
// same row slot (first 4KB of the 8KB row => ldp = 4096 u16 elements).
// Causal-aware I/O: skip loads past s, skip stores past the PV read range (s|127).
__global__ __launch_bounds__(256) void softmax_causal(float* __restrict__ sc) {
  int r = blockIdx.x;          // 0..8191
  int s = r & 2047;
  float* row = sc + (size_t)r * 2048;
  int tid = threadIdx.x;
  int t0 = tid * 8;
  f4v x0 = {-1e30f, -1e30f, -1e30f, -1e30f};
  f4v x1 = {-1e30f, -1e30f, -1e30f, -1e30f};
  if (t0 <= s)     x0 = reinterpret_cast<const f4v*>(row)[tid * 2];
  if (t0 + 4 <= s) x1 = reinterpret_cast<const f4v*>(row)[tid * 2 + 1];
  float v[8] = {x0[0], x0[1], x0[2], x0[3], x1[0], x1[1], x1[2], x1[3]};
  float mx = -1e30f;
  #pragma unroll
  for (int j = 0; j < 8; ++j) {
    v[j] = ((t0 + j) <= s) ? v[j] : -1e30f;
    mx = fmaxf(mx, v[j]);
  }
  #pragma unroll
  for (int o = 32; o; o >>= 1) mx = fmaxf(mx, __shfl_xor(mx, o, 64));
  __shared__ float red[8];
  if ((tid & 63) == 0) red[tid >> 6] = mx;
  __syncthreads();
  mx = fmaxf(fmaxf(red[0], red[1]), fmaxf(red[2], red[3]));
  float p[8];
  float sum = 0.f;
  #pragma unroll
  for (int j = 0; j < 8; ++j) {
    p[j] = ((t0 + j) <= s) ? __expf(v[j] - mx) : 0.f;
    sum += p[j];
  }
  #pragma unroll
  for (int o = 32; o; o >>= 1) sum += __shfl_xor(sum, o, 64);
  if ((tid & 63) == 0) red[4 + (tid >> 6)] = sum;
  __syncthreads();
  sum = red[4] + red[5] + red[6] + red[7];
  float inv = 1.0f / sum;
  u16x8 o8;
  #pragma unroll
  for (int j = 0; j < 8; ++j) o8[j] = f2bf(p[j] * inv);
  if (t0 <= (s | 127))   // PV reads cols < (bm+1)*128 only
    reinterpret_cast<u16x8*>(row)[tid] = o8;
}

// ---------------------------------------------------------------- launcher
extern "C" void kernel_launch(void* const* d_in, const int* in_sizes, int n_in,
                              void* d_out, int out_size, void* d_ws, size_t ws_size,
                              hipStream_t stream) {
  const float* q  = (const float*)d_in[0];
  const float* k  = (const float*)d_in[1];
  const float* v  = (const float*)d_in[2];
  // d_in[3] = attn_mask (causal tril) — handled analytically
  const float* Wq = (const float*)d_in[4];
  const float* Wk = (const float*)d_in[5];
  const float* Wv = (const float*)d_in[6];
  float* out = (float*)d_out;
  char* ws = (char*)d_ws;

  const size_t MB = 1024ull * 1024ull;
  u16* qb  = (u16*)(ws + 0 * MB);    // 48MB x/k/v bf16 (dead after proj)
  u16* wqb = (u16*)(ws + 48 * MB);   // 6MB  weights bf16 (dead after proj)
  u16* Vp  = (u16*)(ws + 54 * MB);   // 16MB (dead after transpose)
  u16* Vt  = (u16*)(ws + 70 * MB);   // 16MB
  u16* Kp  = (u16*)(ws + 86 * MB);   // 16MB
  u16* Qp  = (u16*)(ws + 102 * MB);  // 16MB  -> peak 118MB
  float* sc = (float*)ws;            // 64MB, overlays dead casts+weights+Vp

  // 1. casts (2 launches)
  cast3_f32_bf16<<<dim3(4096, 1, 3), 256, 0, stream>>>(q, k, v, qb, 8ull * MB);
  cast3_f32_bf16<<<dim3(512, 1, 3), 256, 0, stream>>>(Wq, Wk, Wv, wqb, 1ull * MB);

  // 2. all 3 projections, one flat XCD-swizzled launch (1536 blocks)
  gemm_bt<u16, 3><<<1536, 256, 0, stream>>>(
      qb, wqb, Qp, 1024, 1024, 1024, 1024,
      8ull * MB, 1ull * MB, 0, 1.0f, Kp, Vp);

  // 3. V transpose -> Vt[4][1024][2048]
  transpose_bf16k<<<dim3(16, 32, 4), 256, 0, stream>>>(Vp, Vt);

  // 4. QK^T (scaled, triangular-packed, XCD-swizzled) -> scores f32 [4][2048][2048]
  gemm_bt<float, 1><<<544, 256, 0, stream>>>(
      Qp, Kp, sc, 1024, 1024, 1024, 2048,
      (size_t)2048 * 1024, (size_t)2048 * 1024, (size_t)2048 * 2048, 0.03125f,
      nullptr, nullptr);

  // 5. causal softmax, bf16 P written in place (ldp = 4096 u16)
  softmax_causal<<<8192, 256, 0, stream>>>(sc);

  // 6. PV: P[2048][2048](lda 4096) . Vt[1024][2048]^T -> out f32, longest-first
  gemm_bt<float, 2><<<512, 256, 0, stream>>>(
      (u16*)ws, Vt, out, 2048, 4096, 2048, 1024,
      (size_t)2048 * 4096, (size_t)1024 * 2048, (size_t)2048 * 1024, 1.0f,
      nullptr, nullptr);
}